// Round 1
// baseline (319.919 us; speedup 1.0000x reference)
//
#include <hip/hip_runtime.h>
#include <stdint.h>

#define B_ 2
#define S_ 2048
#define DIM_ 2048
#define H_ 16
#define KVH_ 4
#define HD_ 128

typedef short short8 __attribute__((ext_vector_type(8)));
typedef float f4 __attribute__((ext_vector_type(4)));
typedef float f16v __attribute__((ext_vector_type(16)));
typedef unsigned int uint2v __attribute__((ext_vector_type(2)));
typedef unsigned short u16;

// softmax scale folded into Q at attn load: 1/sqrt(128) * log2(e)
#define KSCALE (0.08838834764831845f * 1.4426950408889634f)

__device__ __forceinline__ float bf2f(u16 u) {
    union { unsigned int i; float f; } c; c.i = ((unsigned int)u) << 16; return c.f;
}
__device__ __forceinline__ u16 f2bf(float f) {
    union { float f; unsigned int i; } c; c.f = f;
    return (u16)((c.i + 0x7fffu + ((c.i >> 16) & 1u)) >> 16);
}
__device__ __forceinline__ unsigned pk_bf16(float lo, float hi) {
    unsigned r;
    asm("v_cvt_pk_bf16_f32 %0, %1, %2" : "=v"(r) : "v"(lo), "v"(hi));
    return r;
}

// async global->LDS, 16B per lane; LDS dest is wave-uniform base + lane*16
#define GLDS16(gp, lp) \
    __builtin_amdgcn_global_load_lds((const __attribute__((address_space(1))) unsigned int*)(gp), \
                                     (__attribute__((address_space(3))) unsigned int*)(lp), 16, 0, 0)

// ---------------- fused fp32 -> bf16 cast of all 5 tensors ----------------
__global__ void cast_all(const float* __restrict__ x,  const float* __restrict__ wq,
                         const float* __restrict__ wk, const float* __restrict__ wv,
                         const float* __restrict__ wo,
                         u16* __restrict__ xb, u16* __restrict__ wqkvb, u16* __restrict__ wob) {
    int i = blockIdx.x * 256 + threadIdx.x;   // float4 index, total 4718592
    const float4* src; ushort4* dst; int j;
    if (i < 2097152)      { src = (const float4*)x;  dst = (ushort4*)xb;                 j = i; }
    else if (i < 3145728) { src = (const float4*)wq; dst = (ushort4*)wqkvb;              j = i - 2097152; }
    else if (i < 3407872) { src = (const float4*)wk; dst = (ushort4*)wqkvb + 1048576;    j = i - 3145728; }
    else if (i < 3670016) { src = (const float4*)wv; dst = (ushort4*)wqkvb + 1310720;    j = i - 3407872; }
    else                  { src = (const float4*)wo; dst = (ushort4*)wob;                j = i - 3670016; }
    float4 v = src[j];
    ushort4 o;
    o.x = f2bf(v.x); o.y = f2bf(v.y); o.z = f2bf(v.z); o.w = f2bf(v.w);
    dst[j] = o;
}

// ---------------- GEMM: C[M,N] = A[M,K] @ W[N,K]^T, m97 structure, XCD-swizzled ----------------
template<bool OUT_BF16, int NBX>
__global__ __launch_bounds__(256) void gemm_bt(const u16* __restrict__ A,
                                               const u16* __restrict__ W,
                                               void* __restrict__ Cout,
                                               int M, int N, int K) {
    __shared__ u16 As[128 * 32];
    __shared__ u16 Bs[128 * 32];
    int t = threadIdx.x, lane = t & 63, w = t >> 6;
    int quad = lane >> 4, l16 = lane & 15;
    int wm = w & 1, wn = w >> 1;
    int bid = blockIdx.x;
    int xcd = bid & 7, grp = bid >> 3;
    int bx = grp % NBX, by = (grp / NBX) * 8 + xcd;
    size_t m0 = (size_t)by * 128, n0 = (size_t)bx * 128;

    int c0 = w * 2;
    int ar = c0 * 16 + (lane >> 2);
    int ac = (lane & 3) * 8;
    const u16* Abase = A + (m0 + ar) * (size_t)K + ac;
    const u16* Bbase = W + (n0 + ar) * (size_t)K + ac;
    u16* Adst = As + c0 * 512;
    u16* Bdst = Bs + c0 * 512;

    f4 acc[4][4];
    #pragma unroll
    for (int i = 0; i < 4; i++)
        #pragma unroll
        for (int j = 0; j < 4; j++) acc[i][j] = (f4){0.f, 0.f, 0.f, 0.f};

    int nk = K >> 5;
    for (int kt = 0; kt < nk; kt++) {
        const u16* ga = Abase + kt * 32;
        const u16* gb = Bbase + kt * 32;
        GLDS16(ga, Adst);
        GLDS16(ga + 16 * (size_t)K, Adst + 512);
        GLDS16(gb, Bdst);
        GLDS16(gb + 16 * (size_t)K, Bdst + 512);
        __syncthreads();
        short8 a[4], b[4];
        #pragma unroll
        for (int i = 0; i < 4; i++) a[i] = *(const short8*)&As[(wm * 64 + i * 16 + l16) * 32 + quad * 8];
        #pragma unroll
        for (int j = 0; j < 4; j++) b[j] = *(const short8*)&Bs[(wn * 64 + j * 16 + l16) * 32 + quad * 8];
        #pragma unroll
        for (int i = 0; i < 4; i++)
            #pragma unroll
            for (int j = 0; j < 4; j++)
                acc[i][j] = __builtin_amdgcn_mfma_f32_16x16x32_bf16(a[i], b[j], acc[i][j], 0, 0, 0);
        __syncthreads();
    }
    #pragma unroll
    for (int i = 0; i < 4; i++) {
        size_t row = m0 + wm * 64 + i * 16 + quad * 4;
        #pragma unroll
        for (int j = 0; j < 4; j++) {
            size_t col = n0 + wn * 64 + j * 16 + l16;
            #pragma unroll
            for (int r = 0; r < 4; r++) {
                if (OUT_BF16) ((u16*)Cout)[(row + r) * N + col] = f2bf(acc[i][j][r]);
                else          ((float*)Cout)[(row + r) * N + col] = acc[i][j][r];
            }
        }
    }
}

// ---------------- pack K (with fused RoPE) into swizzled row-major tiles ----------------
// Tile (bk, kt): Kimg[row 0..63][u 0..15] of 16B units; content at (row,u) is
// K[s=kt*64+row][d8 = u ^ (row&7)] so a linear global_load_lds + XOR'd ds_read_b128
// is bank-conflict-free (rule #21: pre-swizzled source, swizzled read).
__global__ __launch_bounds__(256) void pack_k(const u16* __restrict__ QKV,
                                              const float* __restrict__ freqs,
                                              u16* __restrict__ Kp) {
    int gid = blockIdx.x * 256 + threadIdx.x;   // 262144
    int u = gid & 15, row = (gid >> 4) & 63, kt = (gid >> 10) & 31, bk = gid >> 15;
    int b = bk >> 2, kvh = bk & 3;
    int s = kt * 64 + row;
    int d8 = u ^ (row & 7);
    const u16* src = QKV + (size_t)(b * S_ + s) * 3072 + 2048 + kvh * HD_ + d8 * 8;
    short8 v = *(const short8*)src;
    short8 o;
    #pragma unroll
    for (int jp = 0; jp < 4; jp++) {
        float2 cw = ((const float2*)freqs)[s * 64 + d8 * 4 + jp];
        float x0 = bf2f((u16)v[2 * jp]), x1 = bf2f((u16)v[2 * jp + 1]);
        o[2 * jp]     = (short)f2bf(x0 * cw.x - x1 * cw.y);
        o[2 * jp + 1] = (short)f2bf(x0 * cw.y + x1 * cw.x);
    }
    *(short8*)&Kp[(size_t)gid * 8] = o;
}

// ---------------- pack V transposed (Vt[hd][k]) with same XOR swizzle ----------------
// Tile (bk, kt): Vimg[hd 0..127][u 0..7] of 16B units; content at (hd,u) is
// V[k8 = u ^ (hd&7)][hd] (8 consecutive k).
__global__ __launch_bounds__(256) void pack_v(const u16* __restrict__ QKV, u16* __restrict__ Vp) {
    __shared__ u16 L[64 * 136];
    int bid = blockIdx.x;          // 256 blocks
    int bk = bid & 7, kt = bid >> 3;
    int b = bk >> 2, kvh = bk & 3;
    int t = threadIdx.x;
    const u16* src = QKV + (size_t)(b * S_ + kt * 64) * 3072 + 2560 + kvh * HD_;
    #pragma unroll
    for (int it = 0; it < 4; it++) {
        int idx = t + it * 256;
        int r = idx >> 4, c = idx & 15;
        *(short8*)&L[r * 136 + c * 8] = *(const short8*)(src + (size_t)r * 3072 + c * 8);
    }
    __syncthreads();
    u16* dst = Vp + (size_t)(bk * 32 + kt) * 8192;
    #pragma unroll
    for (int it = 0; it < 4; it++) {
        int idx = t + it * 256;     // 1024 units: hd = idx>>3, u = idx&7
        int hd = idx >> 3, u = idx & 7;
        int k0 = (u ^ (hd & 7)) * 8;
        short8 v;
        #pragma unroll
        for (int jj = 0; jj < 8; jj++) v[jj] = (short)L[(k0 + jj) * 136 + hd];
        *(short8*)&dst[(size_t)idx * 8] = v;
    }
}

// ---------------- Flash attention: swapped-operand 32x32 structure (m214 port) ----------------
// S^T = K.Q^T and O^T = V^T.P^T with mfma_32x32x16 => q-row == lane&31 for both S and O:
// m, ls, rescale, 1/ls are per-lane scalars. P stays in registers (cvt_pk + permlane32_swap
// assembles PV B-fragments). Each wave = one head, 32 q-rows; 4 waves (GQA group) share
// double-buffered K/V tiles (single barrier per 64-kv tile, prefetch issued a full
// iteration early). Defer-max THR=8 makes O-rescale rare. Grid 512: bk=bid&7 pins each
// kv-group to one XCD (L2 locality); blocks (i, i+256) pair q-tiles (63-q', q') so each
// CU's two resident blocks sum to constant causal work.
__global__ __launch_bounds__(256) __attribute__((amdgpu_waves_per_eu(2, 2)))
void attn_kernel(const u16* __restrict__ QKV,
                 const float* __restrict__ freqs,
                 const u16* __restrict__ Kp,
                 const u16* __restrict__ Vp,
                 u16* __restrict__ Ob) {
    __shared__ u16 Ks[2][8192];    // 2 x 16KB K tile [64 rows][128 d], XOR-swizzled
    __shared__ u16 Vs[2][8192];    // 2 x 16KB V^T tile [128 hd][64 k], XOR-swizzled
    int bid = blockIdx.x;          // 512
    int jj_ = bid & 255, half = bid >> 8;
    int bk = jj_ & 7, qpr = jj_ >> 3;        // qpr in [0,32)
    int qb = half ? qpr : 63 - qpr;          // long tiles dispatched first
    int b = bk >> 2, kvh = bk & 3;
    int t = threadIdx.x, lane = t & 63, w = t >> 6;
    int l31 = lane & 31, hi = lane >> 5, l7 = lane & 7;
    int h = kvh * 4 + w;
    int nkt = (qb >> 1) + 1;

    // ---- Q: 32 rows (row = l31), RoPE + KSCALE in-register, B-fragment layout ----
    short8 qf[8];
    {
        int s = qb * 32 + l31;
        const u16* qp = QKV + ((size_t)(b * S_ + s)) * 3072 + h * HD_ + hi * 8;
        const float2* fr2 = (const float2*)freqs;
        #pragma unroll
        for (int ds = 0; ds < 8; ds++) {
            short8 v = *(const short8*)(qp + ds * 16);
            short8 o;
            #pragma unroll
            for (int jp = 0; jp < 4; jp++) {
                float2 cs = fr2[s * 64 + ds * 8 + hi * 4 + jp];
                float x0 = bf2f((u16)v[2 * jp]), x1 = bf2f((u16)v[2 * jp + 1]);
                o[2 * jp]     = (short)f2bf((x0 * cs.x - x1 * cs.y) * KSCALE);
                o[2 * jp + 1] = (short)f2bf((x0 * cs.y + x1 * cs.x) * KSCALE);
            }
            qf[ds] = o;
        }
    }

    float m_i = -3e38f, ls = 0.f;
    f16v o4[4];
    #pragma unroll
    for (int i = 0; i < 4; i++)
        #pragma unroll
        for (int r = 0; r < 16; r++) o4[i][r] = 0.f;

    const u16* Kpb = Kp + (size_t)bk * 32 * 8192;
    const u16* Vpb = Vp + (size_t)bk * 32 * 8192;
    int so = w * 2048 + lane * 8;   // this lane's staging slot (u16 units)

    // initial stage of tile 0 into buffer 0 (wave w stages its 4KB quarter of K and V)
    {
        const u16* ks = Kpb + so;
        const u16* vs = Vpb + so;
        #pragma unroll
        for (int i = 0; i < 4; i++) {
            GLDS16(ks + i * 512, &Ks[0][w * 2048 + i * 512]);
            GLDS16(vs + i * 512, &Vs[0][w * 2048 + i * 512]);
        }
    }

    for (int kt = 0; kt < nkt; kt++) {
        int buf = kt & 1;
        __syncthreads();   // drains the stage of tile kt (issued one iteration ago)
        if (kt + 1 < nkt) {
            int nb = buf ^ 1;
            const u16* ks = Kpb + (size_t)(kt + 1) * 8192 + so;
            const u16* vs = Vpb + (size_t)(kt + 1) * 8192 + so;
            #pragma unroll
            for (int i = 0; i < 4; i++) {
                GLDS16(ks + i * 512, &Ks[nb][w * 2048 + i * 512]);
                GLDS16(vs + i * 512, &Vs[nb][w * 2048 + i * 512]);
            }
        }

        // ---- S^T = K . Q^T : D rows = k-pos (crow layout), cols = q (lane&31) ----
        f16v sacc[2];
        #pragma unroll
        for (int k2 = 0; k2 < 2; k2++)
            #pragma unroll
            for (int r = 0; r < 16; r++) sacc[k2][r] = 0.f;
        #pragma unroll
        for (int ds = 0; ds < 8; ds++) {
            int uK = ((ds * 2 + hi) ^ l7) * 8;
            short8 kf0 = *(const short8*)&Ks[buf][l31 * 128 + uK];
            short8 kf1 = *(const short8*)&Ks[buf][(32 + l31) * 128 + uK];
            sacc[0] = __builtin_amdgcn_mfma_f32_32x32x16_bf16(kf0, qf[ds], sacc[0], 0, 0, 0);
            sacc[1] = __builtin_amdgcn_mfma_f32_32x32x16_bf16(kf1, qf[ds], sacc[1], 0, 0, 0);
        }

        // ---- causal mask, diagonal tile only (lane/reg-local condition) ----
        if (kt == nkt - 1) {
            int off0 = kt * 64 - qb * 32;   // 0 (even qb) or -32 (odd qb)
            #pragma unroll
            for (int k2 = 0; k2 < 2; k2++) {
                #pragma unroll
                for (int r = 0; r < 16; r++) {
                    int colo = off0 + k2 * 32 + (r & 3) + ((r >> 2) << 3) + (hi << 2);
                    if (colo > l31) sacc[k2][r] = -3e38f;
                }
            }
        }

        // ---- online softmax, per-lane scalars; defer-max THR=8 (T13) ----
        float pm = sacc[0][0];
        #pragma unroll
        for (int r = 1; r < 16; r++) pm = fmaxf(pm, sacc[0][r]);
        #pragma unroll
        for (int r = 0; r < 16; r++) pm = fmaxf(pm, sacc[1][r]);
        pm = fmaxf(pm, __shfl_xor(pm, 32, 64));   // pair holds same q-row
        if (__any(pm > m_i + 8.0f)) {             // wave-uniform branch
            float mnew = fmaxf(m_i, pm);
            float al = exp2f(m_i - mnew);
            ls *= al;
            #pragma unroll
            for (int i = 0; i < 4; i++)
                #pragma unroll
                for (int r = 0; r < 16; r++) o4[i][r] *= al;
            m_i = mnew;
        }

        // ---- P = exp2(S - m); assemble PV B-fragments in-register (T12) ----
        short8 pa[4];
        #pragma unroll
        for (int k2 = 0; k2 < 2; k2++) {
            float p[16];
            #pragma unroll
            for (int r = 0; r < 16; r++) {
                p[r] = exp2f(sacc[k2][r] - m_i);
                ls += p[r];
            }
            unsigned W0 = pk_bf16(p[0], p[1]),   W1 = pk_bf16(p[2], p[3]);
            unsigned W2 = pk_bf16(p[4], p[5]),   W3 = pk_bf16(p[6], p[7]);
            unsigned W4 = pk_bf16(p[8], p[9]),   W5 = pk_bf16(p[10], p[11]);
            unsigned W6 = pk_bf16(p[12], p[13]), W7 = pk_bf16(p[14], p[15]);
            uint2v r02 = __builtin_amdgcn_permlane32_swap(W0, W2, false, false);
            uint2v r13 = __builtin_amdgcn_permlane32_swap(W1, W3, false, false);
            uint2v r46 = __builtin_amdgcn_permlane32_swap(W4, W6, false, false);
            uint2v r57 = __builtin_amdgcn_permlane32_swap(W5, W7, false, false);
            union { unsigned u[4]; short8 s8; } flo, fhi;
            flo.u[0] = r02[0]; flo.u[1] = r13[0]; flo.u[2] = r02[1]; flo.u[3] = r13[1];
            fhi.u[0] = r46[0]; fhi.u[1] = r57[0]; fhi.u[2] = r46[1]; fhi.u[3] = r57[1];
            pa[k2 * 2]     = flo.s8;
            pa[k2 * 2 + 1] = fhi.s8;
        }

        // ---- O^T += V^T . P^T : D rows = hd (crow layout), cols = q (lane&31) ----
        #pragma unroll
        for (int ks = 0; ks < 4; ks++) {
            int uV = ((ks * 2 + hi) ^ l7) * 8;
            #pragma unroll
            for (int ht = 0; ht < 4; ht++) {
                short8 vf = *(const short8*)&Vs[buf][(ht * 32 + l31) * 64 + uV];
                o4[ht] = __builtin_amdgcn_mfma_f32_32x32x16_bf16(vf, pa[ks], o4[ht], 0, 0, 0);
            }
        }
    }

    // ---- epilogue: per-lane 1/ls, pack 4-wide, 8B stores ----
    ls += __shfl_xor(ls, 32, 64);
    float rl = 1.0f / ls;
    size_t row = (size_t)b * S_ + qb * 32 + l31;
    u16* op = Ob + row * 2048 + h * HD_;
    #pragma unroll
    for (int ht = 0; ht < 4; ht++) {
        #pragma unroll
        for (int g = 0; g < 4; g++) {
            ushort4 st;
            st.x = f2bf(o4[ht][4 * g + 0] * rl);
            st.y = f2bf(o4[ht][4 * g + 1] * rl);
            st.z = f2bf(o4[ht][4 * g + 2] * rl);
            st.w = f2bf(o4[ht][4 * g + 3] * rl);
            *(ushort4*)&op[ht * 32 + g * 8 + hi * 4] = st;
        }
    }
}

extern "C" void kernel_launch(void* const* d_in, const int* in_sizes, int n_in,
                              void* d_out, int out_size, void* d_ws, size_t ws_size,
                              hipStream_t stream) {
    const float* x     = (const float*)d_in[0];
    const float* freqs = (const float*)d_in[1];
    const float* wq    = (const float*)d_in[2];
    const float* wk    = (const float*)d_in[3];
    const float* wv    = (const float*)d_in[4];
    const float* wo    = (const float*)d_in[5];
    float* out = (float*)d_out;

    char* p = (char*)d_ws;
    u16* xb    = (u16*)p; p += (size_t)4096 * 2048 * 2;   // 16MB
    u16* wqkvb = (u16*)p; p += (size_t)3072 * 2048 * 2;   // 12MB
    u16* wob   = (u16*)p; p += (size_t)2048 * 2048 * 2;   // 8MB
    u16* QKVb  = (u16*)p; p += (size_t)4096 * 3072 * 2;   // 24MB
    u16* Kpb   = (u16*)p; p += (size_t)8 * 32 * 8192 * 2; // 4MB
    u16* Vpb   = (u16*)p; p += (size_t)8 * 32 * 8192 * 2; // 4MB
    u16* attnb = xb;  // reuse: x not needed after QKV GEMM

    cast_all<<<18432, 256, 0, stream>>>(x, wq, wk, wv, wo, xb, wqkvb, wob);

    gemm_bt<true, 24><<<768, 256, 0, stream>>>(xb, wqkvb, QKVb, 4096, 3072, 2048);

    pack_k<<<1024, 256, 0, stream>>>(QKVb, freqs, Kpb);
    pack_v<<<256, 256, 0, stream>>>(QKVb, Vpb);

    attn_kernel<<<512, 256, 0, stream>>>(QKVb, freqs, Kpb, Vpb, attnb);

    gemm_bt<false, 16><<<512, 256, 0, stream>>>(attnb, wob, out, 4096, 2048, 2048);
}

// Round 3
// 317.623 us; speedup vs baseline: 1.0072x; 1.0072x over previous
//
#include <hip/hip_runtime.h>
#include <stdint.h>

#define B_ 2
#define S_ 2048
#define DIM_ 2048
#define H_ 16
#define KVH_ 4
#define HD_ 128

typedef short short8 __attribute__((ext_vector_type(8)));
typedef float f4 __attribute__((ext_vector_type(4)));
typedef float f16v __attribute__((ext_vector_type(16)));
typedef unsigned int uint2v __attribute__((ext_vector_type(2)));
typedef unsigned short u16;

// softmax scale folded into Q at attn load: 1/sqrt(128) * log2(e)
#define KSCALE (0.08838834764831845f * 1.4426950408889634f)

__device__ __forceinline__ float bf2f(u16 u) {
    union { unsigned int i; float f; } c; c.i = ((unsigned int)u) << 16; return c.f;
}
__device__ __forceinline__ u16 f2bf(float f) {
    union { float f; unsigned int i; } c; c.f = f;
    return (u16)((c.i + 0x7fffu + ((c.i >> 16) & 1u)) >> 16);
}
__device__ __forceinline__ unsigned pk_bf16(float lo, float hi) {
    unsigned r;
    asm("v_cvt_pk_bf16_f32 %0, %1, %2" : "=v"(r) : "v"(lo), "v"(hi));
    return r;
}

// async global->LDS, 16B per lane; LDS dest is wave-uniform base + lane*16
#define GLDS16(gp, lp) \
    __builtin_amdgcn_global_load_lds((const __attribute__((address_space(1))) unsigned int*)(gp), \
                                     (__attribute__((address_space(3))) unsigned int*)(lp), 16, 0, 0)

#define BAR()     asm volatile("s_barrier" ::: "memory")
#define WAITLGKM() asm volatile("s_waitcnt lgkmcnt(0)" ::: "memory")

// ---------------- fused fp32 -> bf16 cast of all 5 tensors ----------------
__global__ void cast_all(const float* __restrict__ x,  const float* __restrict__ wq,
                         const float* __restrict__ wk, const float* __restrict__ wv,
                         const float* __restrict__ wo,
                         u16* __restrict__ xb, u16* __restrict__ wqkvb, u16* __restrict__ wob) {
    int i = blockIdx.x * 256 + threadIdx.x;   // float4 index, total 4718592
    const float4* src; ushort4* dst; int j;
    if (i < 2097152)      { src = (const float4*)x;  dst = (ushort4*)xb;                 j = i; }
    else if (i < 3145728) { src = (const float4*)wq; dst = (ushort4*)wqkvb;              j = i - 2097152; }
    else if (i < 3407872) { src = (const float4*)wk; dst = (ushort4*)wqkvb + 1048576;    j = i - 3145728; }
    else if (i < 3670016) { src = (const float4*)wv; dst = (ushort4*)wqkvb + 1310720;    j = i - 3407872; }
    else                  { src = (const float4*)wo; dst = (ushort4*)wob;                j = i - 3670016; }
    float4 v = src[j];
    ushort4 o;
    o.x = f2bf(v.x); o.y = f2bf(v.y); o.z = f2bf(v.z); o.w = f2bf(v.w);
    dst[j] = o;
}

// ---------------- GEMM: 256x256 tile, 8-wave, 4-phase/K-tile, counted-vmcnt pipeline ----
// C[M,N] = A[M,K] @ W[N,K]^T. Plain-HIP port of the m201 8-phase schedule.
//  - LDS: As/Bs[2][256x64] bf16, 128KB, 1 block/CU, 2 waves/SIMD.
//  - 8-slot XOR swizzle (16B unit ^= row&7): applied on the global SOURCE address of
//    global_load_lds (linear LDS dest) and on the ds_read_b128 address (rule #21).
//  - Per K-tile t (buf c=t&1), 4 phases = 4 C-quadrants; each phase:
//      ds_read frags; issue 2 region-stages; s_barrier; s_waitcnt lgkmcnt(0);
//      setprio(1); 16 MFMA; setprio(0); s_barrier.
//  - Region stage schedule (each stage hits a region whose last reads drained >=1
//    phase earlier; cross-wave safety published by the barrier after each vmcnt):
//      ph0: A(t+1) rows{64-127,192-255}   ph1: B(t+1) rows{==32-63 mod 64}
//      ph2: A(t+2) rows{0-63,128-191}     ph3: B(t+2) rows{==0-31 mod 64}
//  - One counted wait per tile: vmcnt(2) at ph3 (leaves only ph2(t)'s 2 stages in
//    flight; everything tile t+1 reads landed). vmcnt(0) only in the 2-tile tail.
template<bool OUT_BF16, int NBX>
__global__ __launch_bounds__(512, 2) void gemm256(const u16* __restrict__ A,
                                                  const u16* __restrict__ W,
                                                  void* __restrict__ Cout,
                                                  int M, int N, int K) {
    __shared__ u16 As[2][16384];
    __shared__ u16 Bs[2][16384];
    int t = threadIdx.x, lane = t & 63, w = t >> 6;          // 8 waves
    int quad = lane >> 4, l16 = lane & 15, l7 = lane & 7;
    int wm = w >> 2, wn = w & 3;                              // 2M x 4N wave grid
    int bid = blockIdx.x;
    int xcd = bid & 7, grp = bid >> 3;
    int bx = grp % NBX, by = (grp / NBX) * 8 + xcd;
    size_t m0 = (size_t)by * 256, n0 = (size_t)bx * 256;

    // staging lane map: row += lane>>3, 16B unit = (lane&7) ^ (lane>>3)  (XOR swizzle)
    int srow = lane >> 3;
    int sunit = (lane & 7) ^ srow;
    int rR0a = (w >> 2) * 64 + (w & 3) * 8;   // strided-region wave base
    const u16* Ag = A + (m0 + srow) * (size_t)K + sunit * 8;
    const u16* Bg = W + (n0 + srow) * (size_t)K + sunit * 8;

#define STG_A(pl, tk, r0) GLDS16(Ag + ((size_t)((r0) + w * 8)) * K + (tk) * 64, (pl) + ((r0) + w * 8) * 64)
#define STG_B(pl, tk, r0) GLDS16(Bg + ((size_t)((r0) + w * 8)) * K + (tk) * 64, (pl) + ((r0) + w * 8) * 64)
#define STG_BR(pl, tk, bse) GLDS16(Bg + ((size_t)((bse) + rR0a)) * K + (tk) * 64, (pl) + ((bse) + rR0a) * 64)

#define LDA(mh) { \
    _Pragma("unroll") for (int i_ = 0; i_ < 4; i_++) \
    _Pragma("unroll") for (int k_ = 0; k_ < 2; k_++) \
        a[i_][k_] = *(const short8*)&pAc[(wm * 128 + (mh) * 64 + i_ * 16 + l16) * 64 + (((quad + 4 * k_) ^ l7) << 3)]; }
#define LDB(nh) { \
    _Pragma("unroll") for (int j_ = 0; j_ < 2; j_++) \
    _Pragma("unroll") for (int k_ = 0; k_ < 2; k_++) \
        b[j_][k_] = *(const short8*)&pBc[(wn * 64 + (nh) * 32 + j_ * 16 + l16) * 64 + (((quad + 4 * k_) ^ l7) << 3)]; }
#define MFMA_Q(mh, nh) { \
    __builtin_amdgcn_s_setprio(1); \
    _Pragma("unroll") for (int i_ = 0; i_ < 4; i_++) \
    _Pragma("unroll") for (int j_ = 0; j_ < 2; j_++) \
    _Pragma("unroll") for (int k_ = 0; k_ < 2; k_++) \
        acc[(mh) * 4 + i_][(nh) * 2 + j_] = __builtin_amdgcn_mfma_f32_16x16x32_bf16( \
            a[i_][k_], b[j_][k_], acc[(mh) * 4 + i_][(nh) * 2 + j_], 0, 0, 0); \
    __builtin_amdgcn_s_setprio(0); }

    f4 acc[8][4];
    #pragma unroll
    for (int i = 0; i < 8; i++)
        #pragma unroll
        for (int j = 0; j < 4; j++) acc[i][j] = (f4){0.f, 0.f, 0.f, 0.f};

    int NT = K >> 6;

    // prologue: fully stage tiles 0 and 1, drain once
    #pragma unroll
    for (int pt = 0; pt < 2; pt++) {
        u16* pa = &As[pt][0]; u16* pb = &Bs[pt][0];
        #pragma unroll
        for (int r0 = 0; r0 < 256; r0 += 64) { STG_A(pa, pt, r0); STG_B(pb, pt, r0); }
    }
    asm volatile("s_waitcnt vmcnt(0)" ::: "memory");
    BAR();

    short8 a[4][2], b[2][2];
    for (int tt = 0; tt < NT; tt++) {
        int c = tt & 1, nc = c ^ 1;
        u16* pAc = &As[c][0];  u16* pBc = &Bs[c][0];
        u16* pAn = &As[nc][0]; u16* pBn = &Bs[nc][0];
        bool s1 = (tt >= 1) & (tt + 1 < NT);
        bool s2 = (tt + 2 < NT);
        // ---- ph0: quadrant (0,0)
        LDA(0); LDB(0);
        if (s1) { STG_A(pAn, tt + 1, 64); STG_A(pAn, tt + 1, 192); }
        BAR(); WAITLGKM(); MFMA_Q(0, 0); BAR();
        // ---- ph1: quadrant (0,1)
        LDB(1);
        if (s1) { STG_BR(pBn, tt + 1, 32); STG_BR(pBn, tt + 1, 160); }
        BAR(); WAITLGKM(); MFMA_Q(0, 1); BAR();
        // ---- ph2: quadrant (1,0)
        LDA(1); LDB(0);
        if (s2) { STG_A(pAc, tt + 2, 0); STG_A(pAc, tt + 2, 128); }
        BAR(); WAITLGKM(); MFMA_Q(1, 0); BAR();
        // ---- ph3: quadrant (1,1); single counted wait per tile
        if (s2) asm volatile("s_waitcnt vmcnt(2)" ::: "memory");
        else    asm volatile("s_waitcnt vmcnt(0)" ::: "memory");
        LDB(1);
        if (s2) { STG_BR(pBc, tt + 2, 0); STG_BR(pBc, tt + 2, 128); }
        BAR(); WAITLGKM(); MFMA_Q(1, 1); BAR();
    }

    #pragma unroll
    for (int i = 0; i < 8; i++) {
        size_t row = m0 + wm * 128 + i * 16 + quad * 4;
        #pragma unroll
        for (int j = 0; j < 4; j++) {
            size_t col = n0 + wn * 64 + j * 16 + l16;
            #pragma unroll
            for (int r = 0; r < 4; r++) {
                if (OUT_BF16) ((u16*)Cout)[(row + r) * (size_t)N + col] = f2bf(acc[i][j][r]);
                else          ((float*)Cout)[(row + r) * (size_t)N + col] = acc[i][j][r];
            }
        }
    }
#undef STG_A
#undef STG_B
#undef STG_BR
#undef LDA
#undef LDB
#undef MFMA_Q
}

// ---------------- pack K (with fused RoPE) into swizzled row-major tiles ----------------
__global__ __launch_bounds__(256) void pack_k(const u16* __restrict__ QKV,
                                              const float* __restrict__ freqs,
                                              u16* __restrict__ Kp) {
    int gid = blockIdx.x * 256 + threadIdx.x;   // 262144
    int u = gid & 15, row = (gid >> 4) & 63, kt = (gid >> 10) & 31, bk = gid >> 15;
    int b = bk >> 2, kvh = bk & 3;
    int s = kt * 64 + row;
    int d8 = u ^ (row & 7);
    const u16* src = QKV + (size_t)(b * S_ + s) * 3072 + 2048 + kvh * HD_ + d8 * 8;
    short8 v = *(const short8*)src;
    short8 o;
    #pragma unroll
    for (int jp = 0; jp < 4; jp++) {
        float2 cw = ((const float2*)freqs)[s * 64 + d8 * 4 + jp];
        float x0 = bf2f((u16)v[2 * jp]), x1 = bf2f((u16)v[2 * jp + 1]);
        o[2 * jp]     = (short)f2bf(x0 * cw.x - x1 * cw.y);
        o[2 * jp + 1] = (short)f2bf(x0 * cw.y + x1 * cw.x);
    }
    *(short8*)&Kp[(size_t)gid * 8] = o;
}

// ---------------- pack V transposed (Vt[hd][k]) with same XOR swizzle ----------------
__global__ __launch_bounds__(256) void pack_v(const u16* __restrict__ QKV, u16* __restrict__ Vp) {
    __shared__ u16 L[64 * 136];
    int bid = blockIdx.x;          // 256 blocks
    int bk = bid & 7, kt = bid >> 3;
    int b = bk >> 2, kvh = bk & 3;
    int t = threadIdx.x;
    const u16* src = QKV + (size_t)(b * S_ + kt * 64) * 3072 + 2560 + kvh * HD_;
    #pragma unroll
    for (int it = 0; it < 4; it++) {
        int idx = t + it * 256;
        int r = idx >> 4, c = idx & 15;
        *(short8*)&L[r * 136 + c * 8] = *(const short8*)(src + (size_t)r * 3072 + c * 8);
    }
    __syncthreads();
    u16* dst = Vp + (size_t)(bk * 32 + kt) * 8192;
    #pragma unroll
    for (int it = 0; it < 4; it++) {
        int idx = t + it * 256;     // 1024 units: hd = idx>>3, u = idx&7
        int hd = idx >> 3, u = idx & 7;
        int k0 = (u ^ (hd & 7)) * 8;
        short8 v;
        #pragma unroll
        for (int jj = 0; jj < 8; jj++) v[jj] = (short)L[(k0 + jj) * 136 + hd];
        *(short8*)&dst[(size_t)idx * 8] = v;
    }
}

// ---------------- Flash attention: swapped-operand 32x32 structure ----------------
__global__ __launch_bounds__(256) __attribute__((amdgpu_waves_per_eu(2, 2)))
void attn_kernel(const u16* __restrict__ QKV,
                 const float* __restrict__ freqs,
                 const u16* __restrict__ Kp,
                 const u16* __restrict__ Vp,
                 u16* __restrict__ Ob) {
    __shared__ u16 Ks[2][8192];    // 2 x 16KB K tile [64 rows][128 d], XOR-swizzled
    __shared__ u16 Vs[2][8192];    // 2 x 16KB V^T tile [128 hd][64 k], XOR-swizzled
    int bid = blockIdx.x;          // 512
    int jj_ = bid & 255, half = bid >> 8;
    int bk = jj_ & 7, qpr = jj_ >> 3;        // qpr in [0,32)
    int qb = half ? qpr : 63 - qpr;          // long tiles dispatched first
    int b = bk >> 2, kvh = bk & 3;
    int t = threadIdx.x, lane = t & 63, w = t >> 6;
    int l31 = lane & 31, hi = lane >> 5, l7 = lane & 7;
    int h = kvh * 4 + w;
    int nkt = (qb >> 1) + 1;

    // ---- Q: 32 rows (row = l31), RoPE + KSCALE in-register, B-fragment layout ----
    short8 qf[8];
    {
        int s = qb * 32 + l31;
        const u16* qp = QKV + ((size_t)(b * S_ + s)) * 3072 + h * HD_ + hi * 8;
        const float2* fr2 = (const float2*)freqs;
        #pragma unroll
        for (int ds = 0; ds < 8; ds++) {
            short8 v = *(const short8*)(qp + ds * 16);
            short8 o;
            #pragma unroll
            for (int jp = 0; jp < 4; jp++) {
                float2 cs = fr2[s * 64 + ds * 8 + hi * 4 + jp];
                float x0 = bf2f((u16)v[2 * jp]), x1 = bf2f((u16)v[2 * jp + 1]);
                o[2 * jp]     = (short)f2bf((x0 * cs.x - x1 * cs.y) * KSCALE);
                o[2 * jp + 1] = (short)f2bf((x0 * cs.y + x1 * cs.x) * KSCALE);
            }
            qf[ds] = o;
        }
    }

    float m_i = -3e38f, ls = 0.f;
    f16v o4[4];
    #pragma unroll
    for (int i = 0; i < 4; i++)
        #pragma unroll
        for (int r = 0; r < 16; r++) o4[i][r] = 0.f;

    const u16* Kpb = Kp + (size_t)bk * 32 * 8192;
    const u16* Vpb = Vp + (size_t)bk * 32 * 8192;
    int so = w * 2048 + lane * 8;   // this lane's staging slot (u16 units)

    // initial stage of tile 0 into buffer 0 (wave w stages its 4KB quarter of K and V)
    {
        const u16* ks = Kpb + so;
        const u16* vs = Vpb + so;
        #pragma unroll
        for (int i = 0; i < 4; i++) {
            GLDS16(ks + i * 512, &Ks[0][w * 2048 + i * 512]);
            GLDS16(vs + i * 512, &Vs[0][w * 2048 + i * 512]);
        }
    }

    for (int kt = 0; kt < nkt; kt++) {
        int buf = kt & 1;
        __syncthreads();   // drains the stage of tile kt (issued one iteration ago)
        if (kt + 1 < nkt) {
            int nb = buf ^ 1;
            const u16* ks = Kpb + (size_t)(kt + 1) * 8192 + so;
            const u16* vs = Vpb + (size_t)(kt + 1) * 8192 + so;
            #pragma unroll
            for (int i = 0; i < 4; i++) {
                GLDS16(ks + i * 512, &Ks[nb][w * 2048 + i * 512]);
                GLDS16(vs + i * 512, &Vs[nb][w * 2048 + i * 512]);
            }
        }

        // ---- S^T = K . Q^T : D rows = k-pos (crow layout), cols = q (lane&31) ----
        f16v sacc[2];
        #pragma unroll
        for (int k2 = 0; k2 < 2; k2++)
            #pragma unroll
            for (int r = 0; r < 16; r++) sacc[k2][r] = 0.f;
        #pragma unroll
        for (int ds = 0; ds < 8; ds++) {
            int uK = ((ds * 2 + hi) ^ l7) * 8;
            short8 kf0 = *(const short8*)&Ks[buf][l31 * 128 + uK];
            short8 kf1 = *(const short8*)&Ks[buf][(32 + l31) * 128 + uK];
            sacc[0] = __builtin_amdgcn_mfma_f32_32x32x16_bf16(kf0, qf[ds], sacc[0], 0, 0, 0);
            sacc[1] = __builtin_amdgcn_mfma_f32_32x32x16_bf16(kf1, qf[ds], sacc[1], 0, 0, 0);
        }

        // ---- causal mask, diagonal tile only ----
        if (kt == nkt - 1) {
            int off0 = kt * 64 - qb * 32;
            #pragma unroll
            for (int k2 = 0; k2 < 2; k2++) {
                #pragma unroll
                for (int r = 0; r < 16; r++) {
                    int colo = off0 + k2 * 32 + (r & 3) + ((r >> 2) << 3) + (hi << 2);
                    if (colo > l31) sacc[k2][r] = -3e38f;
                }
            }
        }

        // ---- online softmax, per-lane scalars; defer-max THR=8 (T13) ----
        float pm = sacc[0][0];
        #pragma unroll
        for (int r = 1; r < 16; r++) pm = fmaxf(pm, sacc[0][r]);
        #pragma unroll
        for (int r = 0; r < 16; r++) pm = fmaxf(pm, sacc[1][r]);
        pm = fmaxf(pm, __shfl_xor(pm, 32, 64));
        if (__any(pm > m_i + 8.0f)) {
            float mnew = fmaxf(m_i, pm);
            float al = exp2f(m_i - mnew);
            ls *= al;
            #pragma unroll
            for (int i = 0; i < 4; i++)
                #pragma unroll
                for (int r = 0; r < 16; r++) o4[i][r] *= al;
            m_i = mnew;
        }

        // ---- P = exp2(S - m); assemble PV B-fragments in-register (T12) ----
        short8 pa[4];
        #pragma unroll
        for (int k2 = 0; k2 < 2; k2++) {
            float p[16];
            #pragma unroll
            for (int r = 0; r < 16; r++) {
                p[r] = exp2f(sacc[k2][r] - m_i);
                ls += p[r];
            }
            unsigned W0 = pk_bf16(p[0], p[1]),   W1 = pk_bf16(p[2], p[3]);
            unsigned W2 = pk_bf16(p[4], p[5]),   W3 = pk_bf16(p[6], p[7]);
            unsigned W4 = pk_bf16(p[8], p[9]),   W5 = pk_bf16(p[10], p[11]);
            unsigned W6 = pk_bf16(p[12], p[13]), W7 = pk_bf16(p[14], p[15]);
            uint2v r02 = __builtin_amdgcn_permlane32_swap(W0, W2, false, false);
            uint2v r13 = __builtin_amdgcn_permlane32_swap(W1, W3, false, false);
            uint2v r46 = __builtin_amdgcn_permlane32_swap(W4, W6, false, false);
            uint2v r57 = __builtin_amdgcn_permlane32_swap(W5, W7, false, false);
            union { unsigned u[4]; short8 s8; } flo, fhi;
            flo.u[0] = r02[0]; flo.u[1] = r13[0]; flo.u[2] = r02[1]; flo.u[3] = r13[1];
            fhi.u[0] = r46[0]; fhi.u[1] = r57[0]; fhi.u[2] = r46[1]; fhi.u[3] = r57[1];
            pa[k2 * 2]     = flo.s8;
            pa[k2 * 2 + 1] = fhi.s8;
        }

        // ---- O^T += V^T . P^T ----
        #pragma unroll
        for (int ks = 0; ks < 4; ks++) {
            int uV = ((ks * 2 + hi) ^ l7) * 8;
            #pragma unroll
            for (int ht = 0; ht < 4; ht++) {
                short8 vf = *(const short8*)&Vs[buf][(ht * 32 + l31) * 64 + uV];
                o4[ht] = __builtin_amdgcn_mfma_f32_32x32x16_bf16(vf, pa[ks], o4[ht], 0, 0, 0);
            }
        }
    }

    // ---- epilogue ----
    ls += __shfl_xor(ls, 32, 64);
    float rl = 1.0f / ls;
    size_t row = (size_t)b * S_ + qb * 32 + l31;
    u16* op = Ob + row * 2048 + h * HD_;
    #pragma unroll
    for (int ht = 0; ht < 4; ht++) {
        #pragma unroll
        for (int g = 0; g < 4; g++) {
            ushort4 st;
            st.x = f2bf(o4[ht][4 * g + 0] * rl);
            st.y = f2bf(o4[ht][4 * g + 1] * rl);
            st.z = f2bf(o4[ht][4 * g + 2] * rl);
            st.w = f2bf(o4[ht][4 * g + 3] * rl);
            *(ushort4*)&op[ht * 32 + g * 8 + hi * 4] = st;
        }
    }
}

extern "C" void kernel_launch(void* const* d_in, const int* in_sizes, int n_in,
                              void* d_out, int out_size, void* d_ws, size_t ws_size,
                              hipStream_t stream) {
    const float* x     = (const float*)d_in[0];
    const float* freqs = (const float*)d_in[1];
    const float* wq    = (const float*)d_in[2];
    const float* wk    = (const float*)d_in[3];
    const float* wv    = (const float*)d_in[4];
    const float* wo    = (const float*)d_in[5];
    float* out = (float*)d_out;

    char* p = (char*)d_ws;
    u16* xb    = (u16*)p; p += (size_t)4096 * 2048 * 2;   // 16MB
    u16* wqkvb = (u16*)p; p += (size_t)3072 * 2048 * 2;   // 12MB
    u16* wob   = (u16*)p; p += (size_t)2048 * 2048 * 2;   // 8MB
    u16* QKVb  = (u16*)p; p += (size_t)4096 * 3072 * 2;   // 24MB
    u16* Kpb   = (u16*)p; p += (size_t)8 * 32 * 8192 * 2; // 4MB
    u16* Vpb   = (u16*)p; p += (size_t)8 * 32 * 8192 * 2; // 4MB
    u16* attnb = xb;  // reuse: x not needed after QKV GEMM

    cast_all<<<18432, 256, 0, stream>>>(x, wq, wk, wv, wo, xb, wqkvb, wob);

    gemm256<true, 12><<<192, 512, 0, stream>>>(xb, wqkvb, QKVb, 4096, 3072, 2048);

    pack_k<<<1024, 256, 0, stream>>>(QKVb, freqs, Kpb);
    pack_v<<<256, 256, 0, stream>>>(QKVb, Vpb);

    attn_kernel<<<512, 256, 0, stream>>>(QKVb, freqs, Kpb, Vpb, attnb);

    gemm256<false, 8><<<128, 512, 0, stream>>>(attnb, wob, out, 4096, 2048, 2048);
}